// Round 3
// baseline (1993.893 us; speedup 1.0000x reference)
//
#include <hip/hip_runtime.h>
#include <hip/hip_cooperative_groups.h>

namespace cg = cooperative_groups;

#define NN 2048
#define MM 2048
#define KC 8
#define DD 64

#define LN2F    0.6931471805599453f
#define INVLN2F 1.4426950408889634f

// unified cost buffer segments (element offsets)
#define SEG_XY 0
#define SEG_YX (NN*MM)
#define SEG_XX (2*NN*MM)
#define SEG_YY (2*NN*MM + NN*NN)
#define C_TOTAL (2*NN*MM + NN*NN + MM*MM)

#define TOTROWS (2*(NN+MM))

struct Params {
  const float* x; const float* centers; const float* ftarg;
  const float* y; const int* predy;
  float* out;
  int* pred_x; int* cnt_x; int* cnt_y; int* off_x; int* off_y;
  int* fill_x; int* fill_y; int* pc_x; int* pc_y;
  int* boxy; int* boxx; int* boyy;
  float* Xp; float* Yp; float* xn; float* yn;
  float* Call;
  int4*  meta;     // per-row: {coff, hoff, len, bitcast(hc)}
  float* fin;      // per-row final-contribution scale (0 if invalid)
  float* Fab; float* Gab; float* Faa; float* Gbb;   // each 2*len (ping-pong)
  float* la; float* lb; int* valid;
  float* acc;
};

__device__ __forceinline__ float wredmax(float v){
  #pragma unroll
  for(int m=32;m>=1;m>>=1) v = fmaxf(v, __shfl_xor(v,m,64));
  return v;
}
__device__ __forceinline__ float wredsum(float v){
  #pragma unroll
  for(int m=32;m>=1;m>>=1) v += __shfl_xor(v,m,64);
  return v;
}

// one-pass wave LSE over a row of length len; returns L = -eps*ln(sum exp(...))
// w(c) = (hc + (hv[c]-Cb[c])*inv_eps) * INVLN2F   (log2 domain)
__device__ __forceinline__ float row_softmin(const float* __restrict__ Cb,
                                             const float* __restrict__ hv,
                                             float hc, float inv_eps, float eps,
                                             int len, int lane)
{
  float wv[8];
  #pragma unroll
  for(int q=0;q<8;q++){
    int c = lane + q*64;
    float w = -3.4e38f;
    if(c < len) w = (hc + (hv[c]-Cb[c])*inv_eps)*INVLN2F;
    wv[q] = w;
  }
  float wmax = wv[0];
  #pragma unroll
  for(int q=1;q<8;q++) wmax = fmaxf(wmax, wv[q]);
  // rare tail (len > 512)
  for(int c=lane+512;c<len;c+=64)
    wmax = fmaxf(wmax, (hc + (hv[c]-Cb[c])*inv_eps)*INVLN2F);
  wmax = wredmax(wmax);

  float s = 0.f;
  #pragma unroll
  for(int q=0;q<8;q++) s += exp2f(wv[q]-wmax);   // exp2(-huge)=0 for padded lanes
  for(int c=lane+512;c<len;c+=64)
    s += exp2f((hc + (hv[c]-Cb[c])*inv_eps)*INVLN2F - wmax);
  s = wredsum(s);

  return (len>0) ? (-eps*LN2F*(wmax + log2f(s))) : 0.f;
}

__global__ void __launch_bounds__(256,4) sinkhorn_all(Params p)
{
  cg::grid_group grid = cg::this_grid();
  const int tid  = threadIdx.x;
  const int gtid = blockIdx.x*blockDim.x + tid;
  const int nth  = gridDim.x*blockDim.x;
  const int lane = tid & 63;
  const int wid  = gtid >> 6;
  const int nwaves = nth >> 6;

  const double EMIN = 0.05*0.05;
  const double S2   = 0.8*0.8;
  int neps = 0;
  { double e = 16.0; while(e > EMIN){ neps++; e *= S2; } neps++; }   // = 21

  __shared__ float bacc;

  // ---------- phase 0: zero init ----------
  for(int i=gtid;i<NN;i+=nth){ p.Fab[i]=0.f; p.Faa[i]=0.f; }
  for(int j=gtid;j<MM;j+=nth){ p.Gab[j]=0.f; p.Gbb[j]=0.f; }
  if(gtid<KC){ p.cnt_x[gtid]=0; p.cnt_y[gtid]=0; p.fill_x[gtid]=0; p.fill_y[gtid]=0; }
  if(gtid==0){ *p.acc = 0.f; }
  grid.sync();

  // ---------- phase 1: kmeans predict + counts ----------
  for(int i=gtid;i<NN;i+=nth){
    const float4* xi = (const float4*)(p.x + i*DD);
    float best = 3.4e38f; int bk = 0;
    for(int k=0;k<KC;k++){
      const float4* ck = (const float4*)(p.centers + k*DD);
      float s = 0.f;
      #pragma unroll
      for(int q=0;q<DD/4;q++){ float4 a=xi[q], b=ck[q];
        float dx=a.x-b.x, dy=a.y-b.y, dz=a.z-b.z, dw=a.w-b.w;
        s += dx*dx+dy*dy+dz*dz+dw*dw; }
      if(s < best){ best = s; bk = k; }
    }
    p.pred_x[i] = bk;
    atomicAdd(&p.cnt_x[bk], 1);
  }
  for(int j=gtid;j<MM;j+=nth){
    atomicAdd(&p.cnt_y[p.predy[j]], 1);
  }
  grid.sync();

  // ---------- phase 2: offsets, log-weights, filling loss ----------
  if(gtid==0){
    int ox=0, oy=0, bxy=0, bxx=0, byy=0;
    float lf = 0.f;
    for(int k=0;k<KC;k++){
      int nk=p.cnt_x[k], mk=p.cnt_y[k];
      p.off_x[k]=ox; p.off_y[k]=oy;
      p.boxy[k]=bxy; p.boxx[k]=bxx; p.boyy[k]=byy;
      ox+=nk; oy+=mk; bxy+=nk*mk; bxx+=nk*nk; byy+=mk*mk;
      p.la[k] = -logf(fmaxf((float)nk,1.f));
      p.lb[k] = -logf(fmaxf((float)mk,1.f));
      p.valid[k] = (nk>0 && mk>0) ? 1 : 0;
      float df = (float)nk/(float)NN - p.ftarg[k];
      lf += df*df;
    }
    p.off_x[KC]=ox; p.off_y[KC]=oy;
    *p.acc += lf/(float)KC;
  }
  grid.sync();

  // ---------- phase 3: pack points by cluster ----------
  for(int i=gtid;i<NN;i+=nth){
    int k = p.pred_x[i];
    int pos = p.off_x[k] + atomicAdd(&p.fill_x[k],1);
    p.pc_x[pos] = k;
    const float4* xi = (const float4*)(p.x + i*DD);
    float4* dst = (float4*)(p.Xp + pos*DD);
    float s=0.f;
    #pragma unroll
    for(int q=0;q<DD/4;q++){ float4 v=xi[q]; dst[q]=v;
      s += v.x*v.x+v.y*v.y+v.z*v.z+v.w*v.w; }
    p.xn[pos]=s;
  }
  for(int j=gtid;j<MM;j+=nth){
    int k = p.predy[j];
    int pos = p.off_y[k] + atomicAdd(&p.fill_y[k],1);
    p.pc_y[pos] = k;
    const float4* yj = (const float4*)(p.y + j*DD);
    float4* dst = (float4*)(p.Yp + pos*DD);
    float s=0.f;
    #pragma unroll
    for(int q=0;q<DD/4;q++){ float4 v=yj[q]; dst[q]=v;
      s += v.x*v.x+v.y*v.y+v.z*v.z+v.w*v.w; }
    p.yn[pos]=s;
  }
  grid.sync();

  // ---------- phase 4a: build packed per-cluster cost blocks ----------
  for(int k=0;k<KC;k++){
    const int nk=p.cnt_x[k], mk=p.cnt_y[k];
    const float4* Xb=(const float4*)(p.Xp + p.off_x[k]*DD);
    const float4* Yb=(const float4*)(p.Yp + p.off_y[k]*DD);
    const float* xnb=p.xn+p.off_x[k];
    const float* ynb=p.yn+p.off_y[k];
    int tot = nk*mk;
    for(int t=gtid;t<tot;t+=nth){
      int r=t/mk, c=t-r*mk;
      const float4* a=Xb+r*(DD/4); const float4* b=Yb+c*(DD/4);
      float dot=0.f;
      #pragma unroll
      for(int q=0;q<DD/4;q++){ float4 av=a[q], bv=b[q];
        dot += av.x*bv.x + av.y*bv.y + av.z*bv.z + av.w*bv.w; }
      float cst = 0.5f*fmaxf(xnb[r]+ynb[c]-2.f*dot, 0.f);
      p.Call[SEG_XY + p.boxy[k] + t]        = cst;
      p.Call[SEG_YX + p.boxy[k] + c*nk + r] = cst;
    }
    tot = nk*nk;
    for(int t=gtid;t<tot;t+=nth){
      int r=t/nk, c=t-r*nk;
      const float4* a=Xb+r*(DD/4); const float4* b=Xb+c*(DD/4);
      float dot=0.f;
      #pragma unroll
      for(int q=0;q<DD/4;q++){ float4 av=a[q], bv=b[q];
        dot += av.x*bv.x + av.y*bv.y + av.z*bv.z + av.w*bv.w; }
      p.Call[SEG_XX + p.boxx[k] + t] = 0.5f*fmaxf(xnb[r]+xnb[c]-2.f*dot, 0.f);
    }
    tot = mk*mk;
    for(int t=gtid;t<tot;t+=nth){
      int r=t/mk, c=t-r*mk;
      const float4* a=Yb+r*(DD/4); const float4* b=Yb+c*(DD/4);
      float dot=0.f;
      #pragma unroll
      for(int q=0;q<DD/4;q++){ float4 av=a[q], bv=b[q];
        dot += av.x*bv.x + av.y*bv.y + av.z*bv.z + av.w*bv.w; }
      p.Call[SEG_YY + p.boyy[k] + t] = 0.5f*fmaxf(ynb[r]+ynb[c]-2.f*dot, 0.f);
    }
  }

  // ---------- phase 4b: per-row metadata (iteration-invariant) ----------
  for(int row=gtid; row<TOTROWS; row+=nth){
    int grp, pidx;
    if(row < NN){ grp=0; pidx=row; }
    else if(row < NN+MM){ grp=1; pidx=row-NN; }
    else if(row < 2*NN+MM){ grp=2; pidx=row-NN-MM; }
    else { grp=3; pidx=row-2*NN-MM; }

    int k, coff, hoff, len; float hc, fv;
    if(grp==0){ k=p.pc_x[pidx]; int r=pidx-p.off_x[k]; len=p.cnt_y[k];
      coff=SEG_XY+p.boxy[k]+r*len; hoff=p.off_y[k]; hc=p.lb[k];
      fv = p.valid[k] ?  1.f/(float)p.cnt_x[k] : 0.f; }
    else if(grp==1){ k=p.pc_y[pidx]; int r=pidx-p.off_y[k]; len=p.cnt_x[k];
      coff=SEG_YX+p.boxy[k]+r*len; hoff=p.off_x[k]; hc=p.la[k];
      fv = p.valid[k] ?  1.f/(float)p.cnt_y[k] : 0.f; }
    else if(grp==2){ k=p.pc_x[pidx]; int r=pidx-p.off_x[k]; len=p.cnt_x[k];
      coff=SEG_XX+p.boxx[k]+r*len; hoff=p.off_x[k]; hc=p.la[k];
      fv = p.valid[k] ? -1.f/(float)p.cnt_x[k] : 0.f; }
    else { k=p.pc_y[pidx]; int r=pidx-p.off_y[k]; len=p.cnt_y[k];
      coff=SEG_YY+p.boyy[k]+r*len; hoff=p.off_y[k]; hc=p.lb[k];
      fv = p.valid[k] ? -1.f/(float)p.cnt_y[k] : 0.f; }
    p.meta[row] = make_int4(coff, hoff, len, __float_as_int(hc));
    p.fin[row]  = fv;
  }
  grid.sync();

  // ---------- phase 5: 21 eps-scaling Jacobi iterations ----------
  double e_run = 16.0;
  int cur = 0;
  for(int it=0; it<neps; ++it){
    float eps = (it==neps-1) ? (float)EMIN : (float)e_run;
    e_run *= S2;
    float inv_eps = 1.0f/eps;
    const float* Fab_o=p.Fab+cur*NN; float* Fab_n=p.Fab+(1-cur)*NN;
    const float* Gab_o=p.Gab+cur*MM; float* Gab_n=p.Gab+(1-cur)*MM;
    const float* Faa_o=p.Faa+cur*NN; float* Faa_n=p.Faa+(1-cur)*NN;
    const float* Gbb_o=p.Gbb+cur*MM; float* Gbb_n=p.Gbb+(1-cur)*MM;

    for(int row=wid; row<TOTROWS; row+=nwaves){
      int4 mt = p.meta[row];
      int grp = (row>=NN) + (row>=NN+MM) + (row>=2*NN+MM);
      const float* Cb = p.Call + mt.x;
      const float* hb = (grp==0)?Gab_o:(grp==1)?Fab_o:(grp==2)?Faa_o:Gbb_o;
      const float* hv = hb + mt.y;
      float hc = __int_as_float(mt.w);

      float L = row_softmin(Cb, hv, hc, inv_eps, eps, mt.z, lane);

      if(lane==0){
        int pidx = row - ((grp==0)?0:(grp==1)?NN:(grp==2)?(NN+MM):(2*NN+MM));
        if(grp==0)      Fab_n[pidx] = 0.5f*(Fab_o[pidx]+L);
        else if(grp==1) Gab_n[pidx] = 0.5f*(Gab_o[pidx]+L);
        else if(grp==2) Faa_n[pidx] = 0.5f*(Faa_o[pidx]+L);
        else            Gbb_n[pidx] = 0.5f*(Gbb_o[pidx]+L);
      }
    }
    cur ^= 1;
    grid.sync();
  }

  // ---------- phase 6: final extrapolation at eps_min + reduction ----------
  {
    float eps = (float)EMIN;
    float inv_eps = 1.0f/eps;
    const float* Fab_o=p.Fab+cur*NN;
    const float* Gab_o=p.Gab+cur*MM;
    const float* Faa_o=p.Faa+cur*NN;
    const float* Gbb_o=p.Gbb+cur*MM;

    if(tid==0) bacc = 0.f;
    __syncthreads();

    for(int row=wid; row<TOTROWS; row+=nwaves){
      float fv = p.fin[row];
      if(fv == 0.f) continue;
      int4 mt = p.meta[row];
      int grp = (row>=NN) + (row>=NN+MM) + (row>=2*NN+MM);
      const float* Cb = p.Call + mt.x;
      const float* hb = (grp==0)?Gab_o:(grp==1)?Fab_o:(grp==2)?Faa_o:Gbb_o;
      const float* hv = hb + mt.y;
      float hc = __int_as_float(mt.w);

      float L = row_softmin(Cb, hv, hc, inv_eps, eps, mt.z, lane);

      if(lane==0) atomicAdd(&bacc, L*fv);
    }
    __syncthreads();
    if(tid==0 && bacc != 0.f) atomicAdd(p.acc, bacc);
  }
  grid.sync();
  if(gtid==0) p.out[0] = *p.acc;
}

extern "C" void kernel_launch(void* const* d_in, const int* in_sizes, int n_in,
                              void* d_out, int out_size, void* d_ws, size_t ws_size,
                              hipStream_t stream)
{
  Params p;
  p.x       = (const float*)d_in[0];
  p.centers = (const float*)d_in[1];
  p.ftarg   = (const float*)d_in[2];
  p.y       = (const float*)d_in[3];
  p.predy   = (const int*)d_in[4];
  p.out     = (float*)d_out;

  char* w = (char*)d_ws; size_t o = 0;
  auto A = [&](size_t bytes)->char*{ char* r = w + o; o = (o + bytes + 255) & ~(size_t)255; return r; };
  p.pred_x=(int*)A(NN*4);
  p.cnt_x=(int*)A(KC*4);  p.cnt_y=(int*)A(KC*4);
  p.off_x=(int*)A((KC+1)*4); p.off_y=(int*)A((KC+1)*4);
  p.fill_x=(int*)A(KC*4); p.fill_y=(int*)A(KC*4);
  p.pc_x=(int*)A(NN*4);   p.pc_y=(int*)A(MM*4);
  p.boxy=(int*)A(KC*4);   p.boxx=(int*)A(KC*4); p.boyy=(int*)A(KC*4);
  p.Xp=(float*)A((size_t)NN*DD*4); p.Yp=(float*)A((size_t)MM*DD*4);
  p.xn=(float*)A(NN*4);   p.yn=(float*)A(MM*4);
  p.Fab=(float*)A(2*NN*4); p.Gab=(float*)A(2*MM*4);
  p.Faa=(float*)A(2*NN*4); p.Gbb=(float*)A(2*MM*4);
  p.la=(float*)A(KC*4);   p.lb=(float*)A(KC*4); p.valid=(int*)A(KC*4);
  p.acc=(float*)A(4);
  p.meta=(int4*)A((size_t)TOTROWS*16);
  p.fin=(float*)A((size_t)TOTROWS*4);
  p.Call=(float*)A((size_t)C_TOTAL*4);

  // Size the cooperative grid from the runtime's occupancy answer so the
  // launch can never be rejected as too large (the round-2 failure mode:
  // dim3(1024) hardcoded -> hipErrorCooperativeLaunchTooLarge -> no launch,
  // out stayed 0). Host-side queries only; graph-capture-safe.
  int blocksPerCU = 0;
  hipError_t qerr = hipOccupancyMaxActiveBlocksPerMultiprocessor(
      &blocksPerCU, sinkhorn_all, 256, 0);
  int numCU = 0;
  if(hipDeviceGetAttribute(&numCU, hipDeviceAttributeMultiprocessorCount, 0)
     != hipSuccess || numCU <= 0) numCU = 256;
  int grid = (qerr == hipSuccess && blocksPerCU > 0) ? blocksPerCU * numCU : 256;
  if(grid > 1024) grid = 1024;
  if(grid < 1)    grid = 256;

  void* args[] = { &p };
  hipError_t lerr = hipLaunchCooperativeKernel((void*)sinkhorn_all,
                                               dim3(grid), dim3(256), args, 0, stream);
  if(lerr != hipSuccess){
    (void)hipGetLastError();   // clear sticky error, retry at proven-safe size
    hipLaunchCooperativeKernel((void*)sinkhorn_all, dim3(256), dim3(256),
                               args, 0, stream);
  }
}

// Round 4
// 403.041 us; speedup vs baseline: 4.9471x; 4.9471x over previous
//
#include <hip/hip_runtime.h>

#define NN 2048
#define MM 2048
#define KC 8
#define DD 64

#define LN2F    0.6931471805599453f
#define INVLN2F 1.4426950408889634f

// unified cost buffer segments (element offsets)
#define SEG_XY 0
#define SEG_YX (NN*MM)
#define SEG_XX (2*NN*MM)
#define SEG_YY (2*NN*MM + NN*NN)
#define C_TOTAL (2*NN*MM + NN*NN + MM*MM)

#define TOTROWS (2*(NN+MM))

struct Params {
  const float* x; const float* centers; const float* ftarg;
  const float* y; const int* predy;
  float* out;
  int* pred_x; int* cnt_x; int* cnt_y; int* off_x; int* off_y;
  int* fill_x; int* fill_y; int* pc_x; int* pc_y;
  int* boxy; int* boxx; int* boyy; int* tot;   // tot[0..2] = totXY, totXX, totYY
  float* Xp; float* Yp; float* xn; float* yn;
  float* Call;
  int4*  meta;     // per-row: {coff, hoff, len, bitcast(hc)}
  float* fin;      // per-row final-contribution scale (0 if invalid)
  float* Fab; float* Gab; float* Faa; float* Gbb;   // each 2*len (ping-pong)
  float* la; float* lb; int* valid;
  float* acc;
};

__device__ __forceinline__ float wredmax(float v){
  #pragma unroll
  for(int m=32;m>=1;m>>=1) v = fmaxf(v, __shfl_xor(v,m,64));
  return v;
}
__device__ __forceinline__ float wredsum(float v){
  #pragma unroll
  for(int m=32;m>=1;m>>=1) v += __shfl_xor(v,m,64);
  return v;
}

// one-pass wave LSE over a row of length len; returns L = -eps*ln(sum exp(...))
__device__ __forceinline__ float row_softmin(const float* __restrict__ Cb,
                                             const float* __restrict__ hv,
                                             float hc, float inv_eps, float eps,
                                             int len, int lane)
{
  float wv[8];
  #pragma unroll
  for(int q=0;q<8;q++){
    int c = lane + q*64;
    float w = -3.4e38f;
    if(c < len) w = (hc + (hv[c]-Cb[c])*inv_eps)*INVLN2F;
    wv[q] = w;
  }
  float wmax = wv[0];
  #pragma unroll
  for(int q=1;q<8;q++) wmax = fmaxf(wmax, wv[q]);
  for(int c=lane+512;c<len;c+=64)                      // rare tail (len > 512)
    wmax = fmaxf(wmax, (hc + (hv[c]-Cb[c])*inv_eps)*INVLN2F);
  wmax = wredmax(wmax);

  float s = 0.f;
  #pragma unroll
  for(int q=0;q<8;q++) s += exp2f(wv[q]-wmax);
  for(int c=lane+512;c<len;c+=64)
    s += exp2f((hc + (hv[c]-Cb[c])*inv_eps)*INVLN2F - wmax);
  s = wredsum(s);

  return (len>0) ? (-eps*LN2F*(wmax + log2f(s))) : 0.f;
}

// ---------- K0: zero init ----------
__global__ void __launch_bounds__(256) k0_init(Params p){
  int gtid = blockIdx.x*blockDim.x + threadIdx.x;
  int nth  = gridDim.x*blockDim.x;
  for(int i=gtid;i<NN;i+=nth){ p.Fab[i]=0.f; p.Faa[i]=0.f; }
  for(int j=gtid;j<MM;j+=nth){ p.Gab[j]=0.f; p.Gbb[j]=0.f; }
  if(gtid<KC){ p.cnt_x[gtid]=0; p.cnt_y[gtid]=0; p.fill_x[gtid]=0; p.fill_y[gtid]=0; }
}

// ---------- K1: kmeans predict + counts ----------
__global__ void __launch_bounds__(256) k1_predict(Params p){
  int gtid = blockIdx.x*blockDim.x + threadIdx.x;
  int nth  = gridDim.x*blockDim.x;
  for(int i=gtid;i<NN;i+=nth){
    const float4* xi = (const float4*)(p.x + i*DD);
    float best = 3.4e38f; int bk = 0;
    for(int k=0;k<KC;k++){
      const float4* ck = (const float4*)(p.centers + k*DD);
      float s = 0.f;
      #pragma unroll
      for(int q=0;q<DD/4;q++){ float4 a=xi[q], b=ck[q];
        float dx=a.x-b.x, dy=a.y-b.y, dz=a.z-b.z, dw=a.w-b.w;
        s += dx*dx+dy*dy+dz*dz+dw*dw; }
      if(s < best){ best = s; bk = k; }
    }
    p.pred_x[i] = bk;
    atomicAdd(&p.cnt_x[bk], 1);
  }
  for(int j=gtid;j<MM;j+=nth) atomicAdd(&p.cnt_y[p.predy[j]], 1);
}

// ---------- K2: serial prefix sums, log-weights, filling loss ----------
__global__ void k2_serial(Params p){
  if(threadIdx.x!=0 || blockIdx.x!=0) return;
  int ox=0, oy=0, bxy=0, bxx=0, byy=0;
  float lf = 0.f;
  for(int k=0;k<KC;k++){
    int nk=p.cnt_x[k], mk=p.cnt_y[k];
    p.off_x[k]=ox; p.off_y[k]=oy;
    p.boxy[k]=bxy; p.boxx[k]=bxx; p.boyy[k]=byy;
    ox+=nk; oy+=mk; bxy+=nk*mk; bxx+=nk*nk; byy+=mk*mk;
    p.la[k] = -logf(fmaxf((float)nk,1.f));
    p.lb[k] = -logf(fmaxf((float)mk,1.f));
    p.valid[k] = (nk>0 && mk>0) ? 1 : 0;
    float df = (float)nk/(float)NN - p.ftarg[k];
    lf += df*df;
  }
  p.off_x[KC]=ox; p.off_y[KC]=oy;
  p.tot[0]=bxy; p.tot[1]=bxx; p.tot[2]=byy;
  *p.acc = lf/(float)KC;           // assignment, not += (ws is poisoned)
}

// ---------- K3: pack points by cluster ----------
__global__ void __launch_bounds__(256) k3_pack(Params p){
  int gtid = blockIdx.x*blockDim.x + threadIdx.x;
  int nth  = gridDim.x*blockDim.x;
  for(int i=gtid;i<NN;i+=nth){
    int k = p.pred_x[i];
    int pos = p.off_x[k] + atomicAdd(&p.fill_x[k],1);
    p.pc_x[pos] = k;
    const float4* xi = (const float4*)(p.x + i*DD);
    float4* dst = (float4*)(p.Xp + pos*DD);
    float s=0.f;
    #pragma unroll
    for(int q=0;q<DD/4;q++){ float4 v=xi[q]; dst[q]=v;
      s += v.x*v.x+v.y*v.y+v.z*v.z+v.w*v.w; }
    p.xn[pos]=s;
  }
  for(int j=gtid;j<MM;j+=nth){
    int k = p.predy[j];
    int pos = p.off_y[k] + atomicAdd(&p.fill_y[k],1);
    p.pc_y[pos] = k;
    const float4* yj = (const float4*)(p.y + j*DD);
    float4* dst = (float4*)(p.Yp + pos*DD);
    float s=0.f;
    #pragma unroll
    for(int q=0;q<DD/4;q++){ float4 v=yj[q]; dst[q]=v;
      s += v.x*v.x+v.y*v.y+v.z*v.z+v.w*v.w; }
    p.yn[pos]=s;
  }
}

__device__ __forceinline__ float dot64(const float4* a, const float4* b){
  float d=0.f;
  #pragma unroll
  for(int q=0;q<DD/4;q++){ float4 av=a[q], bv=b[q];
    d += av.x*bv.x + av.y*bv.y + av.z*bv.z + av.w*bv.w; }
  return d;
}

// ---------- K4: cost blocks (flattened) + per-row metadata ----------
__global__ void __launch_bounds__(256) k4_cost(Params p){
  int gtid = blockIdx.x*blockDim.x + threadIdx.x;
  int nth  = gridDim.x*blockDim.x;

  int boxy[KC+1], boxx[KC+1], boyy[KC+1], cx[KC], cy[KC], ox[KC], oy[KC];
  #pragma unroll
  for(int k=0;k<KC;k++){ boxy[k]=p.boxy[k]; boxx[k]=p.boxx[k]; boyy[k]=p.boyy[k];
    cx[k]=p.cnt_x[k]; cy[k]=p.cnt_y[k]; ox[k]=p.off_x[k]; oy[k]=p.off_y[k]; }
  boxy[KC]=p.tot[0]; boxx[KC]=p.tot[1]; boyy[KC]=p.tot[2];

  // XY (+ transposed YX)
  for(int t=gtid;t<boxy[KC];t+=nth){
    int k=0;
    #pragma unroll
    for(int q=0;q<KC-1;q++) if(t>=boxy[q+1]) k=q+1;
    int mk=cy[k], nk=cx[k];
    int lo=t-boxy[k]; int r=lo/mk, c=lo-r*mk;
    float dot = dot64((const float4*)(p.Xp+(size_t)(ox[k]+r)*DD),
                      (const float4*)(p.Yp+(size_t)(oy[k]+c)*DD));
    float cst = 0.5f*fmaxf(p.xn[ox[k]+r]+p.yn[oy[k]+c]-2.f*dot, 0.f);
    p.Call[SEG_XY + t] = cst;
    p.Call[SEG_YX + boxy[k] + c*nk + r] = cst;
  }
  // XX
  for(int t=gtid;t<boxx[KC];t+=nth){
    int k=0;
    #pragma unroll
    for(int q=0;q<KC-1;q++) if(t>=boxx[q+1]) k=q+1;
    int nk=cx[k];
    int lo=t-boxx[k]; int r=lo/nk, c=lo-r*nk;
    float dot = dot64((const float4*)(p.Xp+(size_t)(ox[k]+r)*DD),
                      (const float4*)(p.Xp+(size_t)(ox[k]+c)*DD));
    p.Call[SEG_XX + t] = 0.5f*fmaxf(p.xn[ox[k]+r]+p.xn[ox[k]+c]-2.f*dot, 0.f);
  }
  // YY
  for(int t=gtid;t<boyy[KC];t+=nth){
    int k=0;
    #pragma unroll
    for(int q=0;q<KC-1;q++) if(t>=boyy[q+1]) k=q+1;
    int mk=cy[k];
    int lo=t-boyy[k]; int r=lo/mk, c=lo-r*mk;
    float dot = dot64((const float4*)(p.Yp+(size_t)(oy[k]+r)*DD),
                      (const float4*)(p.Yp+(size_t)(oy[k]+c)*DD));
    p.Call[SEG_YY + t] = 0.5f*fmaxf(p.yn[oy[k]+r]+p.yn[oy[k]+c]-2.f*dot, 0.f);
  }

  // per-row metadata (iteration-invariant)
  for(int row=gtid; row<TOTROWS; row+=nth){
    int grp = (row>=NN) + (row>=NN+MM) + (row>=2*NN+MM);
    int pidx = row - ((grp==0)?0:(grp==1)?NN:(grp==2)?(NN+MM):(2*NN+MM));
    int k, coff, hoff, len; float hc, fv;
    if(grp==0){ k=p.pc_x[pidx]; int r=pidx-ox[k]; len=cy[k];
      coff=SEG_XY+boxy[k]+r*len; hoff=oy[k]; hc=p.lb[k];
      fv = p.valid[k] ?  1.f/(float)cx[k] : 0.f; }
    else if(grp==1){ k=p.pc_y[pidx]; int r=pidx-oy[k]; len=cx[k];
      coff=SEG_YX+boxy[k]+r*len; hoff=ox[k]; hc=p.la[k];
      fv = p.valid[k] ?  1.f/(float)cy[k] : 0.f; }
    else if(grp==2){ k=p.pc_x[pidx]; int r=pidx-ox[k]; len=cx[k];
      coff=SEG_XX+boxx[k]+r*len; hoff=ox[k]; hc=p.la[k];
      fv = p.valid[k] ? -1.f/(float)cx[k] : 0.f; }
    else { k=p.pc_y[pidx]; int r=pidx-oy[k]; len=cy[k];
      coff=SEG_YY+boyy[k]+r*len; hoff=oy[k]; hc=p.lb[k];
      fv = p.valid[k] ? -1.f/(float)cy[k] : 0.f; }
    p.meta[row] = make_int4(coff, hoff, len, __float_as_int(hc));
    p.fin[row]  = fv;
  }
}

// ---------- per-eps Jacobi step: one wave per row ----------
__global__ void __launch_bounds__(256) k_iter(Params p, float eps, float inv_eps, int cur){
  int row  = blockIdx.x*(blockDim.x>>6) + (threadIdx.x>>6);
  int lane = threadIdx.x & 63;
  int4 mt = p.meta[row];
  int grp = (row>=NN) + (row>=NN+MM) + (row>=2*NN+MM);

  const float* Fab_o=p.Fab+cur*NN; float* Fab_n=p.Fab+(1-cur)*NN;
  const float* Gab_o=p.Gab+cur*MM; float* Gab_n=p.Gab+(1-cur)*MM;
  const float* Faa_o=p.Faa+cur*NN; float* Faa_n=p.Faa+(1-cur)*NN;
  const float* Gbb_o=p.Gbb+cur*MM; float* Gbb_n=p.Gbb+(1-cur)*MM;

  const float* Cb = p.Call + mt.x;
  const float* hb = (grp==0)?Gab_o:(grp==1)?Fab_o:(grp==2)?Faa_o:Gbb_o;
  const float* hv = hb + mt.y;
  float hc = __int_as_float(mt.w);

  float L = row_softmin(Cb, hv, hc, inv_eps, eps, mt.z, lane);

  if(lane==0){
    int pidx = row - ((grp==0)?0:(grp==1)?NN:(grp==2)?(NN+MM):(2*NN+MM));
    if(grp==0)      Fab_n[pidx] = 0.5f*(Fab_o[pidx]+L);
    else if(grp==1) Gab_n[pidx] = 0.5f*(Gab_o[pidx]+L);
    else if(grp==2) Faa_n[pidx] = 0.5f*(Faa_o[pidx]+L);
    else            Gbb_n[pidx] = 0.5f*(Gbb_o[pidx]+L);
  }
}

// ---------- final extrapolation at eps_min + reduction ----------
__global__ void __launch_bounds__(256) k_final(Params p, float eps, float inv_eps, int cur){
  __shared__ float bacc;
  if(threadIdx.x==0) bacc = 0.f;
  __syncthreads();

  int row  = blockIdx.x*(blockDim.x>>6) + (threadIdx.x>>6);
  int lane = threadIdx.x & 63;
  float fv = p.fin[row];
  if(fv != 0.f){
    int4 mt = p.meta[row];
    int grp = (row>=NN) + (row>=NN+MM) + (row>=2*NN+MM);
    const float* hb = (grp==0)?(p.Gab+cur*MM):(grp==1)?(p.Fab+cur*NN)
                     :(grp==2)?(p.Faa+cur*NN):(p.Gbb+cur*MM);
    float L = row_softmin(p.Call+mt.x, hb+mt.y, __int_as_float(mt.w),
                          inv_eps, eps, mt.z, lane);
    if(lane==0) atomicAdd(&bacc, L*fv);
  }
  __syncthreads();
  if(threadIdx.x==0 && bacc != 0.f) atomicAdd(p.acc, bacc);
}

__global__ void k_out(Params p){
  if(threadIdx.x==0 && blockIdx.x==0) p.out[0] = *p.acc;
}

extern "C" void kernel_launch(void* const* d_in, const int* in_sizes, int n_in,
                              void* d_out, int out_size, void* d_ws, size_t ws_size,
                              hipStream_t stream)
{
  Params p;
  p.x       = (const float*)d_in[0];
  p.centers = (const float*)d_in[1];
  p.ftarg   = (const float*)d_in[2];
  p.y       = (const float*)d_in[3];
  p.predy   = (const int*)d_in[4];
  p.out     = (float*)d_out;

  char* w = (char*)d_ws; size_t o = 0;
  auto A = [&](size_t bytes)->char*{ char* r = w + o; o = (o + bytes + 255) & ~(size_t)255; return r; };
  p.pred_x=(int*)A(NN*4);
  p.cnt_x=(int*)A(KC*4);  p.cnt_y=(int*)A(KC*4);
  p.off_x=(int*)A((KC+1)*4); p.off_y=(int*)A((KC+1)*4);
  p.fill_x=(int*)A(KC*4); p.fill_y=(int*)A(KC*4);
  p.pc_x=(int*)A(NN*4);   p.pc_y=(int*)A(MM*4);
  p.boxy=(int*)A(KC*4);   p.boxx=(int*)A(KC*4); p.boyy=(int*)A(KC*4);
  p.tot=(int*)A(4*4);
  p.Xp=(float*)A((size_t)NN*DD*4); p.Yp=(float*)A((size_t)MM*DD*4);
  p.xn=(float*)A(NN*4);   p.yn=(float*)A(MM*4);
  p.Fab=(float*)A(2*NN*4); p.Gab=(float*)A(2*MM*4);
  p.Faa=(float*)A(2*NN*4); p.Gbb=(float*)A(2*MM*4);
  p.la=(float*)A(KC*4);   p.lb=(float*)A(KC*4); p.valid=(int*)A(KC*4);
  p.acc=(float*)A(4);
  p.meta=(int4*)A((size_t)TOTROWS*16);
  p.fin=(float*)A((size_t)TOTROWS*4);
  p.Call=(float*)A((size_t)C_TOTAL*4);

  hipLaunchKernelGGL(k0_init,    dim3(16),   dim3(256), 0, stream, p);
  hipLaunchKernelGGL(k1_predict, dim3(16),   dim3(256), 0, stream, p);
  hipLaunchKernelGGL(k2_serial,  dim3(1),    dim3(64),  0, stream, p);
  hipLaunchKernelGGL(k3_pack,    dim3(16),   dim3(256), 0, stream, p);
  hipLaunchKernelGGL(k4_cost,    dim3(512),  dim3(256), 0, stream, p);

  // eps schedule (double math, mirrors reference)
  const double EMIN = 0.05*0.05, S2 = 0.8*0.8;
  float epsv[40]; int ne = 0;
  { double e = 16.0; while(e > EMIN){ epsv[ne++] = (float)e; e *= S2; } epsv[ne++] = (float)EMIN; }

  for(int it=0; it<ne; ++it){
    float eps = epsv[it], inv = 1.0f/eps;
    int cur = it & 1;
    hipLaunchKernelGGL(k_iter, dim3(TOTROWS/4), dim3(256), 0, stream, p, eps, inv, cur);
  }
  {
    float eps = (float)EMIN, inv = 1.0f/eps;
    int cur = ne & 1;
    hipLaunchKernelGGL(k_final, dim3(TOTROWS/4), dim3(256), 0, stream, p, eps, inv, cur);
  }
  hipLaunchKernelGGL(k_out, dim3(1), dim3(64), 0, stream, p);
}